// Round 10
// baseline (68.779 us; speedup 1.0000x reference)
//
#include <hip/hip_runtime.h>

#define DEV static __device__ __forceinline__

// Compile-time-folded element access (j constant after full unroll).
DEV float elem(const float4& v, int j) {
  switch (j & 3) {
    case 0: return v.x;
    case 1: return v.y;
    case 2: return v.z;
    default: return v.w;
  }
}
DEV void setelem(float4& v, int j, float x) {
  switch (j & 3) {
    case 0: v.x = x; break;
    case 1: v.y = x; break;
    case 2: v.z = x; break;
    default: v.w = x; break;
  }
}

// ---------------------------------------------------------------------------
// Register-resident wave-per-series kernel (P == 12, T % 4 == 0, T <= 4096).
//
// One 64-lane wave owns one series; NO LDS. Lane l owns m in {base,base+1}
// whole periods (<= 6 for T <= 4096); its err window (<= 72 floats) lives in
// a statically-indexed float4 E[18] register array, loaded once and used by
// both pass1 and pass2. VGPRs (~140) bind occupancy at 3 waves/SIMD = 12
// waves/CU — 2x the LDS-staged variant (16.9 KB -> ~6 waves/CU).
//
// The ETS state x = (level, trend, s[0..11]) evolves affinely; over whole
// periods the homogeneous map lives in a closed COMPRESSED 4+14-param family:
//   l  -> l + GL*tr + sum_j (GA - Gf*j) s_j      (c_j affine in j!)
//   tr -> tr + Gf * sum_j s_j
//   s_j-> Gd * s_j
// (composition preserves c_j = A - f*j, and the j-slope's recurrence equals
// Gf's, so one scalar GA replaces c[12]).  Per-lane map: analytic geometric
// sums of d = 1-gamma; particular part (Pl,Pt,Ps[12]): pass1 from zero state.
// A 6-round Kogge-Stone shuffle scan (18 floats/round) composes the 64 lane
// maps; lane l applies the exclusive prefix to x0 and pass2 emits y directly
// to global (lane-contiguous float4 writes, L2-merged).
// ---------------------------------------------------------------------------
__global__ __launch_bounds__(64, 3) void ets_reg(
    const float* __restrict__ alpha_, const float* __restrict__ beta_,
    const float* __restrict__ gamma_, const float* __restrict__ lvl0,
    const float* __restrict__ tr0, const float* __restrict__ seas0,
    const float* __restrict__ obs, const float* __restrict__ err,
    float* __restrict__ out, int T)
{
  constexpr int MAXP = 6;  // max periods/lane for T<=4096 (nper<=341)

  const int n = blockIdx.x;
  const int lane = threadIdx.x;

  const float a = alpha_[n], b = beta_[n], g = gamma_[n];
  const float ab = a * b, ig = 1.0f - g;

  const int nper = T / 12;
  const int base = nper >> 6, rem = nper & 63;
  const int m  = base + (lane < rem ? 1 : 0);    // periods this lane owns
  const int p0 = lane * base + min(lane, rem);   // first period
  const float* er = err + (size_t)n * T + (size_t)p0 * 12;
  const float* ob = obs + (size_t)n * T + (size_t)p0 * 12;
  float*       yo = out + (size_t)n * T + (size_t)p0 * 12;

  // ---- load err window into registers (static indices only) ---------------
  float4 E[MAXP * 3];
#pragma unroll
  for (int u = 0; u < MAXP; ++u) {
    if (u < m) {
      const float4* e4 = reinterpret_cast<const float4*>(er + u * 12);
      E[u * 3 + 0] = e4[0]; E[u * 3 + 1] = e4[1]; E[u * 3 + 2] = e4[2];
    }
  }

  // ---- pass1: particular solution from zero state -------------------------
  float l = 0.f, tr = 0.f, s[12];
#pragma unroll
  for (int j = 0; j < 12; ++j) s[j] = 0.f;
#pragma unroll
  for (int u = 0; u < MAXP; ++u) {
    if (u < m) {
#pragma unroll
      for (int j = 0; j < 12; ++j) {
        float e  = elem(E[u * 3 + (j >> 2)], j);
        float se = s[j] + e;
        float lt = l + tr;
        l  = fmaf(a, se, lt);
        tr = fmaf(ab, se, tr);
        s[j] = fmaf(g, e, ig * s[j]);
      }
    }
  }

  // ---- analytic homogeneous map for this lane's m periods -----------------
  float S0 = 0.f, S1 = 0.f, dk = 1.f;
#pragma unroll
  for (int k = 0; k < MAXP; ++k) {
    if (k < m) { S0 += dk; S1 += (float)k * dk; dk *= ig; }
  }
  float GL = 12.0f * (float)m;                   // l += GL * tr
  float Gd = dk;                                 // s_j *= Gd  (m==0 -> 1)
  float Gf = ab * S0;                            // tr += Gf * sum(s)
  float GA = fmaf(a, S0, ab * ((GL - 1.0f) * S0 - 12.0f * S1));  // c_j = GA - Gf*j
  float Pl = l, Pt = tr, Ps[12];
#pragma unroll
  for (int j = 0; j < 12; ++j) Ps[j] = s[j];

  // ---- Kogge-Stone inclusive scan of compressed affine maps ---------------
  // compose(first = o (earlier lanes), second = current):
  //   S = sum(oPs), W = sum(j*oPs_j), dot = GA*S - Gf*W
  //   Pl' = oPl + GL*oPt + dot + Pl ;  Pt' = oPt + Gf*S + Pt
  //   Ps'_j = Gd*oPs_j + Ps_j ;  GA' = oA + GL*of + GA*od
  //   Gf' = of + Gf*od ;  Gd' = od*Gd ;  GL' = oL + GL
#pragma unroll
  for (int dlt = 1; dlt < 64; dlt <<= 1) {
    float oL  = __shfl_up(GL, dlt, 64);
    float od  = __shfl_up(Gd, dlt, 64);
    float of  = __shfl_up(Gf, dlt, 64);
    float oA  = __shfl_up(GA, dlt, 64);
    float oPl = __shfl_up(Pl, dlt, 64);
    float oPt = __shfl_up(Pt, dlt, 64);
    float oPs[12];
#pragma unroll
    for (int j = 0; j < 12; ++j) oPs[j] = __shfl_up(Ps[j], dlt, 64);
    if (lane >= dlt) {
      float S = 0.f, W = 0.f;
#pragma unroll
      for (int j = 0; j < 12; ++j) {
        S += oPs[j];
        W = fmaf((float)j, oPs[j], W);
      }
      float dot = GA * S - Gf * W;
      float nPl = oPl + GL * oPt + dot + Pl;
      float nPt = fmaf(Gf, S, oPt) + Pt;
#pragma unroll
      for (int j = 0; j < 12; ++j) Ps[j] = fmaf(Gd, oPs[j], Ps[j]);
      GA = oA + GL * of + GA * od;
      Pl = nPl; Pt = nPt;
      Gf = of + Gf * od;
      Gd = od * Gd;
      GL = oL + GL;
    }
  }

  // ---- apply inclusive map to x0 -> state AFTER this lane's chunk ---------
  const float l0 = lvl0[n], tr00 = tr0[n];
  float s0[12];
#pragma unroll
  for (int j = 0; j < 12; ++j) s0[j] = seas0[(size_t)n * 12 + j];
  float ss = 0.f, sw = 0.f;
#pragma unroll
  for (int j = 0; j < 12; ++j) {
    ss += s0[j];
    sw = fmaf((float)j, s0[j], sw);
  }
  float cdot = GA * ss - Gf * sw;
  float yl = l0 + GL * tr00 + cdot + Pl;
  float yt = fmaf(Gf, ss, tr00) + Pt;
  float ys[12];
#pragma unroll
  for (int j = 0; j < 12; ++j) ys[j] = fmaf(Gd, s0[j], Ps[j]);

  // exclusive shift: lane's true initial state = previous lane's inclusive
  l  = __shfl_up(yl, 1, 64);
  tr = __shfl_up(yt, 1, 64);
#pragma unroll
  for (int j = 0; j < 12; ++j) s[j] = __shfl_up(ys[j], 1, 64);
  if (lane == 0) {
    l = l0; tr = tr00;
#pragma unroll
    for (int j = 0; j < 12; ++j) s[j] = s0[j];
  }

  // ---- pass2: emit y = cur + 0.1*obs directly to global -------------------
#pragma unroll
  for (int u = 0; u < MAXP; ++u) {
    if (u < m) {
      const float4* o4 = reinterpret_cast<const float4*>(ob + u * 12);
      float4 O0 = o4[0], O1 = o4[1], O2 = o4[2];
      float4 y0, y1, y2;
#pragma unroll
      for (int j = 0; j < 12; ++j) {
        float e  = elem(E[u * 3 + (j >> 2)], j);
        float oj = elem(j < 4 ? O0 : (j < 8 ? O1 : O2), j);
        float lt  = l + tr;
        float cur = lt + s[j];
        float4& yd = (j < 4 ? y0 : (j < 8 ? y1 : y2));
        setelem(yd, j, fmaf(oj, 0.1f, cur));
        float se = s[j] + e;
        l  = fmaf(a, se, lt);
        tr = fmaf(ab, se, tr);
        s[j] = fmaf(g, e, ig * s[j]);
      }
      float4* y4 = reinterpret_cast<float4*>(yo + u * 12);
      y4[0] = y0; y4[1] = y1; y4[2] = y2;
    }
  }

  // tail (< 12 steps, slot phase 0) continues from the last lane's state
  if (lane == 63) {
    int tt = nper * 12;
    int tail = T - tt;
    if (tail > 0) {
      const float* et = err + (size_t)n * T + tt;
      const float* ot = obs + (size_t)n * T + tt;
      float*       yt2 = out + (size_t)n * T + tt;
#pragma unroll
      for (int j = 0; j < 11; ++j) {
        if (j < tail) {
          float e = et[j], oj = ot[j];
          float lt  = l + tr;
          float cur = lt + s[j];
          yt2[j] = fmaf(oj, 0.1f, cur);
          float se = s[j] + e;
          l  = fmaf(a, se, lt);
          tr = fmaf(ab, se, tr);
          s[j] = fmaf(g, e, ig * s[j]);
        }
      }
    }
  }
}

// ---------------------------------------------------------------------------
// Generic fallback (any P/T): one thread per series, seasonal state in LDS.
// ---------------------------------------------------------------------------
__global__ void ets_gen(
    const float* __restrict__ alpha_, const float* __restrict__ beta_,
    const float* __restrict__ gamma_, const float* __restrict__ lvl0,
    const float* __restrict__ tr0, const float* __restrict__ seas0,
    const float* __restrict__ obs, const float* __restrict__ err,
    float* __restrict__ out, int N, int T, int P)
{
  extern __shared__ float smem[];
  int n = blockIdx.x * blockDim.x + threadIdx.x;
  if (n >= N) return;
  float* s = smem + (size_t)threadIdx.x * P;
  for (int j = 0; j < P; ++j) s[j] = seas0[(size_t)n * P + j];

  float a = alpha_[n], b = beta_[n], g = gamma_[n];
  float ia = 1.0f - a, ib = 1.0f - b, ig = 1.0f - g;
  float level = lvl0[n], trend = tr0[n];

  const float* on = obs + (size_t)n * T;
  const float* er = err + (size_t)n * T;
  float*       yo = out + (size_t)n * T;

  int idx = 0;
  for (int t = 0; t < T; ++t) {
    float onj = on[t], ej = er[t];
    float sj  = s[idx];
    float cur = level + trend + sj;
    yo[t] = fmaf(onj, 0.1f, cur);
    float lt  = level + trend;
    float nl  = fmaf(a, cur + ej, ia * lt);
    float nt  = fmaf(b, nl - level, ib * trend);
    s[idx]    = fmaf(g, ej, ig * sj);
    level = nl; trend = nt;
    if (++idx == P) idx = 0;
  }
}

extern "C" void kernel_launch(void* const* d_in, const int* in_sizes, int n_in,
                              void* d_out, int out_size, void* d_ws, size_t ws_size,
                              hipStream_t stream) {
  (void)n_in; (void)out_size; (void)d_ws; (void)ws_size;
  const float* alpha = (const float*)d_in[0];
  const float* beta  = (const float*)d_in[1];
  const float* gamma = (const float*)d_in[2];
  const float* lvl0  = (const float*)d_in[3];
  const float* tr0   = (const float*)d_in[4];
  const float* seas0 = (const float*)d_in[5];
  const float* obs   = (const float*)d_in[6];
  const float* err   = (const float*)d_in[7];
  float* y = (float*)d_out;

  int N = in_sizes[0];
  int P = in_sizes[5] / N;
  int T = in_sizes[6] / N;

  if (P == 12 && (T % 4) == 0 && T >= 12 && T <= 4096) {
    ets_reg<<<dim3(N), dim3(64), 0, stream>>>(
        alpha, beta, gamma, lvl0, tr0, seas0, obs, err, y, T);
  } else {
    int bs = 64;
    size_t sh = (size_t)bs * (size_t)P * sizeof(float);
    ets_gen<<<dim3((N + bs - 1) / bs), dim3(bs), sh, stream>>>(
        alpha, beta, gamma, lvl0, tr0, seas0, obs, err, y, N, T, P);
  }
}

// Round 11
// 44.318 us; speedup vs baseline: 1.5519x; 1.5519x over previous
//
#include <hip/hip_runtime.h>

#define DEV static __device__ __forceinline__

// Skewed LDS addressing: physical = j + j/32. Breaks the 12/24/36-float lane
// strides into ~2-way conflicts. Max phys for T=4096: 4095 + 127 = 4222 < 4224.
#define SKEW(j) ((j) + ((j) >> 5))

// ---------------------------------------------------------------------------
// 2-wave-per-series kernel (P == 12, T % 4 == 0, 12 <= T <= 4096).
//
// One block (128 threads = 2 waves) owns one series; err staged to LDS
// (16.9 KB + totals = 17 KB -> 9 blocks/CU = 18 waves/CU). nper periods are
// split over 128 lanes (m in {base, base+1}; m<=3 for T<=4096), halving the
// per-lane serial chain vs the 64-lane variant (72 vs 144 steps).
//
// The ETS state x = (level, trend, s[0..11]) evolves affinely; over whole
// periods the homogeneous map lives in the closed COMPRESSED 18-float family
//   l  -> l + GL*tr + sum_j (GA - Gf*j) s_j     (c_j affine in j)
//   tr -> tr + Gf * sum_j s_j
//   s_j-> Gd * s_j
// (+ particular part Pl, Pt, Ps[12]); composition preserves the form
// (hardware-validated round 10). Per-lane map: analytic geometric sums of
// d = 1-gamma; particular part: pass1 from zero state. Per-wave 6-round
// Kogge-Stone scan (18 shuffles/round); wave-0 total crosses via LDS and is
// applied by wave 1 as a STATE transform; pass2 writes `cur` into the
// consumed err slots; store-out fuses y = cur + 0.1*obs coalesced.
//
// NO min-waves launch-bounds cap (round-7 lesson: a tight VGPR cap spilled
// the scan state to scratch, WRITE_SIZE 65.5 -> 389 MB, 2.5x slowdown).
// ---------------------------------------------------------------------------
__global__ __launch_bounds__(128) void ets_w2(
    const float* __restrict__ alpha_, const float* __restrict__ beta_,
    const float* __restrict__ gamma_, const float* __restrict__ lvl0,
    const float* __restrict__ tr0, const float* __restrict__ seas0,
    const float* __restrict__ obs, const float* __restrict__ err,
    float* __restrict__ out, int T)
{
  __shared__ float er_s[4224];   // err, recycled for `cur` in pass2
  __shared__ float tot[20];      // wave-0 inclusive map (18 floats)

  const int n = blockIdx.x;
  const int tid = threadIdx.x;
  const int lane = tid & 63;
  const int wv = tid >> 6;

  const float4* ER4 = reinterpret_cast<const float4*>(err + (size_t)n * T);
  const float4* OB4 = reinterpret_cast<const float4*>(obs + (size_t)n * T);
  const int nf4 = T >> 2;

  // Coalesced stage-in: 2 KB per block load iteration.
  for (int i = tid; i < nf4; i += 128) {
    float4 e = ER4[i];
    int j = i << 2;
    er_s[SKEW(j + 0)] = e.x; er_s[SKEW(j + 1)] = e.y;
    er_s[SKEW(j + 2)] = e.z; er_s[SKEW(j + 3)] = e.w;
  }

  const float a = alpha_[n], b = beta_[n], g = gamma_[n];
  const float ab = a * b, ig = 1.0f - g;

  const int nper = T / 12;
  const int base = nper >> 7, rem = nper & 127;
  const int m  = base + (tid < rem ? 1 : 0);     // periods this lane owns
  const int p0 = tid * base + min(tid, rem);     // first period
  const int t0 = p0 * 12;

  __syncthreads();

  // ---- pass1: particular solution from zero state -------------------------
  float l = 0.f, tr = 0.f, s[12];
#pragma unroll
  for (int j = 0; j < 12; ++j) s[j] = 0.f;
  {
    int t = t0;
    for (int u = 0; u < m; ++u, t += 12) {
#pragma unroll
      for (int j = 0; j < 12; ++j) {
        float e = er_s[SKEW(t + j)];
        float se = s[j] + e;
        float lt = l + tr;
        l  = fmaf(a, se, lt);
        tr = fmaf(ab, se, tr);
        s[j] = fmaf(g, e, ig * s[j]);
      }
    }
  }

  // ---- analytic compressed homogeneous map for this lane's m periods ------
  float S0 = 0.f, S1 = 0.f, dk = 1.f;
  for (int k = 0; k < m; ++k) { S0 += dk; S1 += (float)k * dk; dk *= ig; }
  float GL = 12.0f * (float)m;                   // l += GL * tr
  float Gd = dk;                                 // s_j *= Gd (m==0 -> identity)
  float Gf = ab * S0;                            // tr += Gf * sum(s)
  float GA = fmaf(a, S0, ab * ((GL - 1.0f) * S0 - 12.0f * S1)); // c_j = GA-Gf*j
  float Pl = l, Pt = tr, Ps[12];
#pragma unroll
  for (int j = 0; j < 12; ++j) Ps[j] = s[j];

  // ---- per-wave Kogge-Stone inclusive scan (compressed maps) --------------
  // compose(first = o (earlier lanes), second = current):
  //   S = sum(oPs), W = sum(j*oPs_j), dot = GA*S - Gf*W
  //   Pl' = oPl + GL*oPt + dot + Pl ;  Pt' = oPt + Gf*S + Pt
  //   Ps'_j = Gd*oPs_j + Ps_j ;  GA' = oA + GL*of + GA*od
  //   Gf' = of + Gf*od ;  Gd' = od*Gd ;  GL' = oL + GL
#pragma unroll
  for (int dlt = 1; dlt < 64; dlt <<= 1) {
    float oL  = __shfl_up(GL, dlt, 64);
    float od  = __shfl_up(Gd, dlt, 64);
    float of  = __shfl_up(Gf, dlt, 64);
    float oA  = __shfl_up(GA, dlt, 64);
    float oPl = __shfl_up(Pl, dlt, 64);
    float oPt = __shfl_up(Pt, dlt, 64);
    float oPs[12];
#pragma unroll
    for (int j = 0; j < 12; ++j) oPs[j] = __shfl_up(Ps[j], dlt, 64);
    if (lane >= dlt) {
      float S = 0.f, W = 0.f;
#pragma unroll
      for (int j = 0; j < 12; ++j) {
        S += oPs[j];
        W = fmaf((float)j, oPs[j], W);
      }
      float dot = GA * S - Gf * W;
      float nPl = oPl + GL * oPt + dot + Pl;
      float nPt = fmaf(Gf, S, oPt) + Pt;
#pragma unroll
      for (int j = 0; j < 12; ++j) Ps[j] = fmaf(Gd, oPs[j], Ps[j]);
      GA = oA + GL * of + GA * od;
      Pl = nPl; Pt = nPt;
      Gf = of + Gf * od;
      Gd = od * Gd;
      GL = oL + GL;
    }
  }

  // ---- exchange wave-0 total ----------------------------------------------
  if (wv == 0 && lane == 63) {
    tot[0] = GL; tot[1] = Gd; tot[2] = Gf; tot[3] = GA; tot[4] = Pl; tot[5] = Pt;
#pragma unroll
    for (int j = 0; j < 12; ++j) tot[6 + j] = Ps[j];
  }
  __syncthreads();

  // ---- wave-start state: x0 for wave 0; tot applied to x0 for wave 1 ------
  float xl = lvl0[n], xt = tr0[n], xs[12];
#pragma unroll
  for (int j = 0; j < 12; ++j) xs[j] = seas0[(size_t)n * 12 + j];
  if (wv == 1) {
    float ss = 0.f, sw = 0.f;
#pragma unroll
    for (int j = 0; j < 12; ++j) {
      ss += xs[j];
      sw = fmaf((float)j, xs[j], sw);
    }
    float cdot = tot[3] * ss - tot[2] * sw;
    float nxl = xl + tot[0] * xt + cdot + tot[4];
    float nxt = fmaf(tot[2], ss, xt) + tot[5];
#pragma unroll
    for (int j = 0; j < 12; ++j) xs[j] = fmaf(tot[1], xs[j], tot[6 + j]);
    xl = nxl; xt = nxt;
  }

  // ---- apply inclusive map to wave-start -> state AFTER this lane's chunk -
  float ss = 0.f, sw = 0.f;
#pragma unroll
  for (int j = 0; j < 12; ++j) {
    ss += xs[j];
    sw = fmaf((float)j, xs[j], sw);
  }
  float cdot = GA * ss - Gf * sw;
  float yl = xl + GL * xt + cdot + Pl;
  float yt = fmaf(Gf, ss, xt) + Pt;
  float ys[12];
#pragma unroll
  for (int j = 0; j < 12; ++j) ys[j] = fmaf(Gd, xs[j], Ps[j]);

  // exclusive shift: lane's true initial state = previous lane's inclusive;
  // lane 0 of each wave takes its wave-start state.
  l  = __shfl_up(yl, 1, 64);
  tr = __shfl_up(yt, 1, 64);
#pragma unroll
  for (int j = 0; j < 12; ++j) s[j] = __shfl_up(ys[j], 1, 64);
  if (lane == 0) {
    l = xl; tr = xt;
#pragma unroll
    for (int j = 0; j < 12; ++j) s[j] = xs[j];
  }

  // ---- pass2: write `cur` into the consumed err slots ---------------------
  {
    int t = t0;
    for (int u = 0; u < m; ++u, t += 12) {
#pragma unroll
      for (int j = 0; j < 12; ++j) {
        int ad = SKEW(t + j);
        float e = er_s[ad];
        float lt = l + tr;
        float cur = lt + s[j];
        er_s[ad] = cur;                 // y minus the 0.1*obs term
        float se = s[j] + e;
        l  = fmaf(a, se, lt);
        tr = fmaf(ab, se, tr);
        s[j] = fmaf(g, e, ig * s[j]);
      }
    }
  }
  // tail (< 12 steps, slot phase 0) continues from the last lane's state
  if (tid == 127) {
    int tt = nper * 12;
    int tail = T - tt;
#pragma unroll
    for (int j = 0; j < 11; ++j) {
      if (j < tail) {
        int ad = SKEW(tt + j);
        float e = er_s[ad];
        float lt = l + tr;
        float cur = lt + s[j];
        er_s[ad] = cur;
        float se = s[j] + e;
        l  = fmaf(a, se, lt);
        tr = fmaf(ab, se, tr);
        s[j] = fmaf(g, e, ig * s[j]);
      }
    }
  }

  __syncthreads();

  // Coalesced store-out, fusing y = cur + 0.1*obs with a coalesced obs read.
  float4* Y4 = reinterpret_cast<float4*>(out + (size_t)n * T);
  for (int i = tid; i < nf4; i += 128) {
    float4 o = OB4[i];
    int j = i << 2;
    float4 v = make_float4(fmaf(o.x, 0.1f, er_s[SKEW(j + 0)]),
                           fmaf(o.y, 0.1f, er_s[SKEW(j + 1)]),
                           fmaf(o.z, 0.1f, er_s[SKEW(j + 2)]),
                           fmaf(o.w, 0.1f, er_s[SKEW(j + 3)]));
    Y4[i] = v;
  }
}

// ---------------------------------------------------------------------------
// Generic fallback (any P/T): one thread per series, seasonal state in LDS.
// ---------------------------------------------------------------------------
__global__ void ets_gen(
    const float* __restrict__ alpha_, const float* __restrict__ beta_,
    const float* __restrict__ gamma_, const float* __restrict__ lvl0,
    const float* __restrict__ tr0, const float* __restrict__ seas0,
    const float* __restrict__ obs, const float* __restrict__ err,
    float* __restrict__ out, int N, int T, int P)
{
  extern __shared__ float smem[];
  int n = blockIdx.x * blockDim.x + threadIdx.x;
  if (n >= N) return;
  float* s = smem + (size_t)threadIdx.x * P;
  for (int j = 0; j < P; ++j) s[j] = seas0[(size_t)n * P + j];

  float a = alpha_[n], b = beta_[n], g = gamma_[n];
  float ia = 1.0f - a, ib = 1.0f - b, ig = 1.0f - g;
  float level = lvl0[n], trend = tr0[n];

  const float* on = obs + (size_t)n * T;
  const float* er = err + (size_t)n * T;
  float*       yo = out + (size_t)n * T;

  int idx = 0;
  for (int t = 0; t < T; ++t) {
    float onj = on[t], ej = er[t];
    float sj  = s[idx];
    float cur = level + trend + sj;
    yo[t] = fmaf(onj, 0.1f, cur);
    float lt  = level + trend;
    float nl  = fmaf(a, cur + ej, ia * lt);
    float nt  = fmaf(b, nl - level, ib * trend);
    s[idx]    = fmaf(g, ej, ig * sj);
    level = nl; trend = nt;
    if (++idx == P) idx = 0;
  }
}

extern "C" void kernel_launch(void* const* d_in, const int* in_sizes, int n_in,
                              void* d_out, int out_size, void* d_ws, size_t ws_size,
                              hipStream_t stream) {
  (void)n_in; (void)out_size; (void)d_ws; (void)ws_size;
  const float* alpha = (const float*)d_in[0];
  const float* beta  = (const float*)d_in[1];
  const float* gamma = (const float*)d_in[2];
  const float* lvl0  = (const float*)d_in[3];
  const float* tr0   = (const float*)d_in[4];
  const float* seas0 = (const float*)d_in[5];
  const float* obs   = (const float*)d_in[6];
  const float* err   = (const float*)d_in[7];
  float* y = (float*)d_out;

  int N = in_sizes[0];
  int P = in_sizes[5] / N;
  int T = in_sizes[6] / N;

  if (P == 12 && (T % 4) == 0 && T >= 12 && T <= 4096) {
    ets_w2<<<dim3(N), dim3(128), 0, stream>>>(
        alpha, beta, gamma, lvl0, tr0, seas0, obs, err, y, T);
  } else {
    int bs = 64;
    size_t sh = (size_t)bs * (size_t)P * sizeof(float);
    ets_gen<<<dim3((N + bs - 1) / bs), dim3(bs), sh, stream>>>(
        alpha, beta, gamma, lvl0, tr0, seas0, obs, err, y, N, T, P);
  }
}